// Round 12
// baseline (361.742 us; speedup 1.0000x reference)
//
#include <hip/hip_runtime.h>

#define IN_CH  256
#define HCC    256   // HEADS*OUT_CH
#define HEADS  4
#define OUTC   64
#define NEG_SLOPE 0.2f

#define NBUK   512    // dst buckets (rng = ceil(N/512) nodes each)
#define NBLK   64     // partition blocks (segment ~195B -> mostly-full lines)
#define SRC_BITS 17
#define SRC_MASK 0x1FFFF

using short8v = __attribute__((ext_vector_type(8))) short;
using f32x4   = __attribute__((ext_vector_type(4))) float;

__device__ __forceinline__ unsigned short f2bf(float f) {
    unsigned u = __float_as_uint(f);
    unsigned r = (u + 0x7fffu + ((u >> 16) & 1u)) >> 16;  // RNE
    return (unsigned short)r;
}
__device__ __forceinline__ float bf2f(unsigned short b) {
    return __uint_as_float((unsigned)b << 16);
}
__device__ __forceinline__ int buk_of(int dst, unsigned M) {
    unsigned s = (unsigned)(((unsigned long long)(unsigned)dst * M) >> 32);
    return (s >= NBUK) ? (NBUK - 1) : (int)s;
}

// ---------------------------------------------------------------------------
// Kernel 0: W [K=256][N=256] fp32 -> WT [N][K] bf16 (tiny, one-time)
// ---------------------------------------------------------------------------
__global__ void k_wt(const float* __restrict__ W,
                     unsigned short* __restrict__ WT) {
    int n = blockIdx.x;
    int k = threadIdx.x;
    WT[n * IN_CH + k] = f2bf(W[(size_t)k * HCC + n]);
}

// ---------------------------------------------------------------------------
// Kernel 1 (fused, BM=128): heterogeneous grid.
//   blocks [0, ngemm):          MFMA GEMM tile 128x256 + fused att logits
//   blocks [ngemm, ngemm+NBLK): dst-bucket histogram (CSR sweep 1)
// BM=128 halves per-output B staging (WT re-read/block) and barrier count.
// ---------------------------------------------------------------------------
__global__ __launch_bounds__(256) void k_gemm_pcnt(
    const float* __restrict__ X, const unsigned short* __restrict__ WT,
    const float* __restrict__ ASRC, const float* __restrict__ ADST,
    unsigned short* __restrict__ XLB, float* __restrict__ a_s,
    float* __restrict__ a_d, int N, int ngemm,
    const int* __restrict__ ei, int* __restrict__ pcnt2d, int E, unsigned M) {
    __shared__ unsigned short Ats[128][72];  // [m][k]
    __shared__ unsigned short Bs[256][72];   // [n][k]
    __shared__ int hbuk[NBUK];

    if (blockIdx.x >= ngemm) {
        // ---- CSR sweep 1: per-(bucket,block) counts via LDS histogram ----
        int bid = blockIdx.x - ngemm;
        int t = threadIdx.x;
        for (int k = t; k < NBUK; k += 256) hbuk[k] = 0;
        __syncthreads();
        int chunk = (E + NBLK - 1) / NBLK;
        int e0 = bid * chunk;
        int e1 = e0 + chunk;
        if (e1 > E) e1 = E;
        for (int i = e0 + t; i < e1; i += 256)
            atomicAdd(&hbuk[buk_of(ei[E + i], M)], 1);
        __syncthreads();
        for (int k = t; k < NBUK; k += 256)
            pcnt2d[k * NBLK + bid] = hbuk[k];
        return;
    }

    // ---- GEMM tile: 128 rows x 256 cols ----
    const int tid = threadIdx.x;
    const int lane = tid & 63;
    const int wid = tid >> 6;
    const int m0 = blockIdx.x * 128;
    const int r16 = lane & 15;
    const int g = lane >> 4;

    f32x4 acc[8][4];
    const f32x4 z = {0.f, 0.f, 0.f, 0.f};
#pragma unroll
    for (int m = 0; m < 8; ++m)
#pragma unroll
        for (int n = 0; n < 4; ++n) acc[m][n] = z;

    for (int kb = 0; kb < IN_CH; kb += 64) {
        // stage A: 128 rows x 64 k, fp32 -> bf16
#pragma unroll
        for (int it = 0; it < 8; ++it) {
            int v = tid + 256 * it;
            int row = v >> 4;          // 0..127
            int c4 = (v & 15) << 2;    // 0..60
            int gr = m0 + row;
            float4 av = make_float4(0.f, 0.f, 0.f, 0.f);
            if (gr < N) av = *(const float4*)(X + (size_t)gr * IN_CH + kb + c4);
            ushort4 ab;
            ab.x = f2bf(av.x); ab.y = f2bf(av.y);
            ab.z = f2bf(av.z); ab.w = f2bf(av.w);
            *(ushort4*)&Ats[row][c4] = ab;
        }
        // stage B: 256 n x 64 k bf16
#pragma unroll
        for (int it = 0; it < 8; ++it) {
            int v = tid + 256 * it;
            int brow = v >> 3;
            int c8 = (v & 7) << 3;
            short8v bv = *(const short8v*)(WT + (size_t)brow * IN_CH + kb + c8);
            *(short8v*)&Bs[brow][c8] = bv;
        }
        __syncthreads();
#pragma unroll
        for (int ks = 0; ks < 2; ++ks) {
            short8v bf[4];
#pragma unroll
            for (int n = 0; n < 4; ++n)
                bf[n] = *(const short8v*)&Bs[wid * 64 + n * 16 + r16][ks * 32 + g * 8];
#pragma unroll
            for (int m = 0; m < 8; ++m) {
                short8v af = *(const short8v*)&Ats[m * 16 + r16][ks * 32 + g * 8];
#pragma unroll
                for (int n = 0; n < 4; ++n)
                    acc[m][n] = __builtin_amdgcn_mfma_f32_16x16x32_bf16(
                        af, bf[n], acc[m][n], 0, 0, 0);
            }
        }
        __syncthreads();
    }

    const int h = wid;
    float asc[4], adc[4];
#pragma unroll
    for (int n = 0; n < 4; ++n) {
        asc[n] = ASRC[h * OUTC + n * 16 + r16];
        adc[n] = ADST[h * OUTC + n * 16 + r16];
    }

    // epilogue: D frag layout col=lane&15, row=(lane>>4)*4+j  [m89-verified]
#pragma unroll
    for (int m = 0; m < 8; ++m) {
#pragma unroll
        for (int j = 0; j < 4; ++j) {
            int row = m0 + m * 16 + g * 4 + j;
            float ds = 0.f, dd = 0.f;
#pragma unroll
            for (int n = 0; n < 4; ++n) {
                ds = fmaf(acc[m][n][j], asc[n], ds);
                dd = fmaf(acc[m][n][j], adc[n], dd);
            }
#pragma unroll
            for (int o = 1; o < 16; o <<= 1) {
                ds += __shfl_xor(ds, o);
                dd += __shfl_xor(dd, o);
            }
            if (row < N) {
                if (r16 == 0) {
                    a_s[(size_t)row * HEADS + h] = ds;
                    a_d[(size_t)row * HEADS + h] = dd;
                }
#pragma unroll
                for (int n = 0; n < 4; ++n) {
                    int col = wid * 64 + n * 16 + r16;
                    XLB[(size_t)row * HCC + col] = f2bf(acc[m][n][j]);
                }
            }
        }
    }
}

// ---------------------------------------------------------------------------
// CSR build v6.2: scan + partition + per-bucket finalize. NBLK=64.
// ---------------------------------------------------------------------------

// scan of the NBUK*NBLK (bucket-major) counts -> base2d + per-bucket pbase
__global__ __launch_bounds__(1024) void k_pscan(const int* __restrict__ pcnt2d,
                                                int* __restrict__ base2d,
                                                int* __restrict__ pbase,
                                                int E) {
    __shared__ int s[1024];
    const int PT = (NBUK * NBLK) / 1024;  // 32 per thread
    int t = threadIdx.x;
    int c[PT];
    int sum = 0;
#pragma unroll
    for (int i = 0; i < PT; ++i) {
        c[i] = pcnt2d[t * PT + i];
        sum += c[i];
    }
    s[t] = sum;
    __syncthreads();
    for (int off = 1; off < 1024; off <<= 1) {
        int x = (t >= off) ? s[t - off] : 0;
        __syncthreads();
        s[t] += x;
        __syncthreads();
    }
    int run = s[t] - sum;  // exclusive
#pragma unroll
    for (int i = 0; i < PT; ++i) {
        int j = t * PT + i;
        base2d[j] = run;
        if ((j & (NBLK - 1)) == 0) pbase[j / NBLK] = run;
        run += c[i];
    }
    if (t == 0) pbase[NBUK] = E;
}

// sweep 2: write packed edges into exact block-private (bucket,block) segs
__global__ __launch_bounds__(256) void k_part2(const int* __restrict__ ei,
                                               const int* __restrict__ base2d,
                                               unsigned* __restrict__ pedges,
                                               int E, unsigned M, int rng) {
    __shared__ int cur[NBUK];
    int t = threadIdx.x;
    for (int k = t; k < NBUK; k += 256)
        cur[k] = base2d[k * NBLK + blockIdx.x];
    __syncthreads();
    int chunk = (E + NBLK - 1) / NBLK;
    int e0 = blockIdx.x * chunk;
    int e1 = e0 + chunk;
    if (e1 > E) e1 = E;
    for (int i = e0 + t; i < e1; i += 256) {
        int src = ei[i];
        int dst = ei[E + i];
        int s = buk_of(dst, M);
        int pos = atomicAdd(&cur[s], 1);  // LDS atomic only
        pedges[pos] = ((unsigned)(dst - s * rng) << SRC_BITS) | (unsigned)src;
    }
}

// per-bucket finalize: LDS histogram + scan -> rowptr, self-loops, eid.
// Bucket k's eid region = [pbase[k] + k*rng, ...) -- closed form, L2-local.
__global__ __launch_bounds__(256) void k_fin(const int* __restrict__ pbase,
                                             const unsigned* __restrict__ pedges,
                                             int* __restrict__ rowptr,
                                             int* __restrict__ eid,
                                             int N, int rng) {
    __shared__ int cntL[256];
    __shared__ int scanL[256];
    __shared__ int fillL[256];
    int k = blockIdx.x;
    int t = threadIdx.x;
    int lo = k * rng;
    if (lo >= N) return;
    int nloc = N - lo;
    if (nloc > rng) nloc = rng;
    int p0 = pbase[k];
    int cnt = pbase[k + 1] - p0;
    cntL[t] = 0;
    __syncthreads();
    for (int i = t; i < cnt; i += 256)
        atomicAdd(&cntL[pedges[p0 + i] >> SRC_BITS], 1);
    __syncthreads();
    int own = (t < nloc) ? cntL[t] + 1 : 0;  // +1 self-loop
    scanL[t] = own;
    __syncthreads();
    for (int off = 1; off < 256; off <<= 1) {
        int x = (t >= off) ? scanL[t - off] : 0;
        __syncthreads();
        scanL[t] += x;
        __syncthreads();
    }
    int excl = scanL[t] - own;
    int gbase = p0 + lo;  // edge prefix + self-loop prefix
    if (t < nloc) {
        rowptr[lo + t] = gbase + excl;
        if (lo + t == N - 1) rowptr[N] = gbase + excl + own;
        eid[gbase + excl] = lo + t;  // self-loop first
        fillL[t] = excl + 1;
    }
    __syncthreads();
    for (int i = t; i < cnt; i += 256) {
        unsigned pk = pedges[p0 + i];
        int dl = (int)(pk >> SRC_BITS);
        int pos = atomicAdd(&fillL[dl], 1);
        eid[gbase + pos] = (int)(pk & SRC_MASK);
    }
}

// ---------------------------------------------------------------------------
// Kernel 3: per-dst softmax + aggregation. One WAVE per node, lane owns 4
// channels. 8-deep edge unroll for gather MLP. No max subtraction (logits
// O(8), fp32 exp safe).
// ---------------------------------------------------------------------------
__global__ __launch_bounds__(256) void k_agg(const int* __restrict__ rowptr,
                                             const int* __restrict__ eid,
                                             const float* __restrict__ a_s,
                                             const float* __restrict__ a_d,
                                             const unsigned short* __restrict__ XLB,
                                             const float* __restrict__ BIAS,
                                             float* __restrict__ OUT, int N) {
    int wid = threadIdx.x >> 6;
    int lane = threadIdx.x & 63;
    int n = blockIdx.x * 4 + wid;
    if (n >= N) return;
    int h = lane >> 4;
    int s0 = rowptr[n];
    int s1 = rowptr[n + 1];
    float adn = a_d[(size_t)n * HEADS + h];
    float s = 0.f;
    float acc0 = 0.f, acc1 = 0.f, acc2 = 0.f, acc3 = 0.f;

    int e = s0;
    for (; e + 8 <= s1; e += 8) {
        int idx[8];
#pragma unroll
        for (int j = 0; j < 8; ++j) idx[j] = eid[e + j];
        float l[8];
#pragma unroll
        for (int j = 0; j < 8; ++j) l[j] = a_s[(size_t)idx[j] * HEADS + h] + adn;
        ushort4 xv[8];
#pragma unroll
        for (int j = 0; j < 8; ++j)
            xv[j] = *(const ushort4*)(XLB + (size_t)idx[j] * HCC + lane * 4);
#pragma unroll
        for (int j = 0; j < 8; ++j) {
            float lj = fmaxf(l[j], NEG_SLOPE * l[j]);
            float p = __expf(lj);
            s += p;
            acc0 = fmaf(p, bf2f(xv[j].x), acc0);
            acc1 = fmaf(p, bf2f(xv[j].y), acc1);
            acc2 = fmaf(p, bf2f(xv[j].z), acc2);
            acc3 = fmaf(p, bf2f(xv[j].w), acc3);
        }
    }
    for (; e + 4 <= s1; e += 4) {
        int idx[4];
#pragma unroll
        for (int j = 0; j < 4; ++j) idx[j] = eid[e + j];
        float l[4];
#pragma unroll
        for (int j = 0; j < 4; ++j) l[j] = a_s[(size_t)idx[j] * HEADS + h] + adn;
        ushort4 xv[4];
#pragma unroll
        for (int j = 0; j < 4; ++j)
            xv[j] = *(const ushort4*)(XLB + (size_t)idx[j] * HCC + lane * 4);
#pragma unroll
        for (int j = 0; j < 4; ++j) {
            float lj = fmaxf(l[j], NEG_SLOPE * l[j]);
            float p = __expf(lj);
            s += p;
            acc0 = fmaf(p, bf2f(xv[j].x), acc0);
            acc1 = fmaf(p, bf2f(xv[j].y), acc1);
            acc2 = fmaf(p, bf2f(xv[j].z), acc2);
            acc3 = fmaf(p, bf2f(xv[j].w), acc3);
        }
    }
    for (; e < s1; ++e) {
        int src = eid[e];
        float l = a_s[(size_t)src * HEADS + h] + adn;
        l = fmaxf(l, NEG_SLOPE * l);
        float p = __expf(l);
        ushort4 xv = *(const ushort4*)(XLB + (size_t)src * HCC + lane * 4);
        s += p;
        acc0 = fmaf(p, bf2f(xv.x), acc0);
        acc1 = fmaf(p, bf2f(xv.y), acc1);
        acc2 = fmaf(p, bf2f(xv.z), acc2);
        acc3 = fmaf(p, bf2f(xv.w), acc3);
    }

    float inv = 1.f / (s + 1e-16f);
    float4 b = *(const float4*)(BIAS + lane * 4);
    float4 o;
    o.x = acc0 * inv + b.x;
    o.y = acc1 * inv + b.y;
    o.z = acc2 * inv + b.z;
    o.w = acc3 * inv + b.w;
    *(float4*)(OUT + (size_t)n * HCC + lane * 4) = o;
}

// ---------------------------------------------------------------------------
extern "C" void kernel_launch(void* const* d_in, const int* in_sizes, int n_in,
                              void* d_out, int out_size, void* d_ws,
                              size_t ws_size, hipStream_t stream) {
    const float* X = (const float*)d_in[0];
    const int* EI = (const int*)d_in[1];
    const float* W = (const float*)d_in[2];
    const float* ASRC = (const float*)d_in[3];
    const float* ADST = (const float*)d_in[4];
    const float* BIAS = (const float*)d_in[5];
    float* OUT = (float*)d_out;

    const int N = in_sizes[0] / IN_CH;
    const int E = in_sizes[1] / 2;
    const int ET = E + N;
    const int rng = (N + NBUK - 1) / NBUK;
    const unsigned M = (unsigned)(((1ULL << 32) + rng - 1) / (unsigned)rng);

    // workspace layout (all 256B aligned)
    char* w = (char*)d_ws;
    auto align = [](size_t x) { return (x + 255) & ~(size_t)255; };
    size_t o = 0;
    unsigned short* xlb = (unsigned short*)(w + o); o += align((size_t)N * HCC * 2);
    unsigned short* wt = (unsigned short*)(w + o);  o += align((size_t)IN_CH * HCC * 2);
    float* a_s = (float*)(w + o); o += align((size_t)N * HEADS * 4);
    float* a_d = (float*)(w + o); o += align((size_t)N * HEADS * 4);
    int* rowptr = (int*)(w + o);  o += align((size_t)(N + 1) * 4);
    int* eid = (int*)(w + o);     o += align((size_t)ET * 4);
    unsigned* pedges = (unsigned*)(w + o); o += align((size_t)E * 4);
    int* pcnt2d = (int*)(w + o);  o += align((size_t)NBUK * NBLK * 4);
    int* base2d = (int*)(w + o);  o += align((size_t)NBUK * NBLK * 4);
    int* pbase = (int*)(w + o);   o += align((NBUK + 1) * 4);

    // 0. W -> WT (bf16, transposed)
    k_wt<<<HCC, IN_CH, 0, stream>>>(W, wt);

    // 1. fused: MFMA GEMM 128x256 (+att logits) || CSR bucket histogram
    int ngemm = (N + 127) / 128;
    k_gemm_pcnt<<<ngemm + NBLK, 256, 0, stream>>>(X, wt, ASRC, ADST, xlb,
                                                  a_s, a_d, N, ngemm, EI,
                                                  pcnt2d, E, M);

    // 2. CSR build v6.2
    k_pscan<<<1, 1024, 0, stream>>>(pcnt2d, base2d, pbase, E);
    k_part2<<<NBLK, 256, 0, stream>>>(EI, base2d, pedges, E, M, rng);
    k_fin<<<NBUK, 256, 0, stream>>>(pbase, pedges, rowptr, eid, N, rng);

    // 3. per-dst softmax + weighted aggregation (one wave per node)
    k_agg<<<(N + 3) / 4, 256, 0, stream>>>(rowptr, eid, a_s, a_d, xlb, BIAS,
                                           OUT, N);
}

// Round 13
// 314.484 us; speedup vs baseline: 1.1503x; 1.1503x over previous
//
#include <hip/hip_runtime.h>

#define IN_CH  256
#define HCC    256   // HEADS*OUT_CH
#define HEADS  4
#define OUTC   64
#define NEG_SLOPE 0.2f

#define NBUK   512    // dst buckets (rng = ceil(N/512) nodes each)
#define NBLK   64     // partition blocks (segment ~195B -> mostly-full lines)
#define SRC_BITS 17
#define SRC_MASK 0x1FFFF

using short8v = __attribute__((ext_vector_type(8))) short;
using f32x4   = __attribute__((ext_vector_type(4))) float;

__device__ __forceinline__ unsigned short f2bf(float f) {
    unsigned u = __float_as_uint(f);
    unsigned r = (u + 0x7fffu + ((u >> 16) & 1u)) >> 16;  // RNE
    return (unsigned short)r;
}
__device__ __forceinline__ float bf2f(unsigned short b) {
    return __uint_as_float((unsigned)b << 16);
}
__device__ __forceinline__ int buk_of(int dst, unsigned M) {
    unsigned s = (unsigned)(((unsigned long long)(unsigned)dst * M) >> 32);
    return (s >= NBUK) ? (NBUK - 1) : (int)s;
}

// ---------------------------------------------------------------------------
// Kernel 0: W [K=256][N=256] fp32 -> WT [N][K] bf16 (tiny, one-time)
// ---------------------------------------------------------------------------
__global__ void k_wt(const float* __restrict__ W,
                     unsigned short* __restrict__ WT) {
    int n = blockIdx.x;
    int k = threadIdx.x;
    WT[n * IN_CH + k] = f2bf(W[(size_t)k * HCC + n]);
}

// ---------------------------------------------------------------------------
// Kernel 1 (fused, BM=64 — R11-proven tile): heterogeneous grid.
//   blocks [0, ngemm):          MFMA GEMM tile 64x256 + fused att logits
//   blocks [ngemm, ngemm+NBLK): dst-bucket histogram (CSR sweep 1)
// BM=128 (R12) was a 2x regression: VGPR 192 + LDS 57KB -> 9% occupancy,
// latency-bound. BM=64 keeps 3 blocks/CU.
// ---------------------------------------------------------------------------
__global__ __launch_bounds__(256) void k_gemm_pcnt(
    const float* __restrict__ X, const unsigned short* __restrict__ WT,
    const float* __restrict__ ASRC, const float* __restrict__ ADST,
    unsigned short* __restrict__ XLB, float* __restrict__ a_s,
    float* __restrict__ a_d, int N, int ngemm,
    const int* __restrict__ ei, int* __restrict__ pcnt2d, int E, unsigned M) {
    __shared__ unsigned short Ats[64][72];   // [m][k]
    __shared__ unsigned short Bs[256][72];   // [n][k]
    __shared__ int hbuk[NBUK];

    if (blockIdx.x >= ngemm) {
        // ---- CSR sweep 1: per-(bucket,block) counts via LDS histogram ----
        int bid = blockIdx.x - ngemm;
        int t = threadIdx.x;
        for (int k = t; k < NBUK; k += 256) hbuk[k] = 0;
        __syncthreads();
        int chunk = (E + NBLK - 1) / NBLK;
        int e0 = bid * chunk;
        int e1 = e0 + chunk;
        if (e1 > E) e1 = E;
        for (int i = e0 + t; i < e1; i += 256)
            atomicAdd(&hbuk[buk_of(ei[E + i], M)], 1);
        __syncthreads();
        for (int k = t; k < NBUK; k += 256)
            pcnt2d[k * NBLK + bid] = hbuk[k];
        return;
    }

    // ---- GEMM tile: 64 rows x 256 cols ----
    const int tid = threadIdx.x;
    const int lane = tid & 63;
    const int wid = tid >> 6;
    const int m0 = blockIdx.x * 64;
    const int r16 = lane & 15;
    const int g = lane >> 4;

    f32x4 acc[4][4];
    const f32x4 z = {0.f, 0.f, 0.f, 0.f};
#pragma unroll
    for (int m = 0; m < 4; ++m)
#pragma unroll
        for (int n = 0; n < 4; ++n) acc[m][n] = z;

    for (int kb = 0; kb < IN_CH; kb += 64) {
#pragma unroll
        for (int it = 0; it < 4; ++it) {
            int v = tid + 256 * it;
            int row = v >> 4;
            int c4 = (v & 15) << 2;
            int gr = m0 + row;
            float4 av = make_float4(0.f, 0.f, 0.f, 0.f);
            if (gr < N) av = *(const float4*)(X + (size_t)gr * IN_CH + kb + c4);
            ushort4 ab;
            ab.x = f2bf(av.x); ab.y = f2bf(av.y);
            ab.z = f2bf(av.z); ab.w = f2bf(av.w);
            *(ushort4*)&Ats[row][c4] = ab;
        }
#pragma unroll
        for (int it = 0; it < 8; ++it) {
            int v = tid + 256 * it;
            int brow = v >> 3;
            int c8 = (v & 7) << 3;
            short8v bv = *(const short8v*)(WT + (size_t)brow * IN_CH + kb + c8);
            *(short8v*)&Bs[brow][c8] = bv;
        }
        __syncthreads();
#pragma unroll
        for (int ks = 0; ks < 2; ++ks) {
            short8v af[4], bf[4];
#pragma unroll
            for (int m = 0; m < 4; ++m)
                af[m] = *(const short8v*)&Ats[m * 16 + r16][ks * 32 + g * 8];
#pragma unroll
            for (int n = 0; n < 4; ++n)
                bf[n] = *(const short8v*)&Bs[wid * 64 + n * 16 + r16][ks * 32 + g * 8];
#pragma unroll
            for (int m = 0; m < 4; ++m)
#pragma unroll
                for (int n = 0; n < 4; ++n)
                    acc[m][n] = __builtin_amdgcn_mfma_f32_16x16x32_bf16(
                        af[m], bf[n], acc[m][n], 0, 0, 0);
        }
        __syncthreads();
    }

    const int h = wid;
    float asc[4], adc[4];
#pragma unroll
    for (int n = 0; n < 4; ++n) {
        asc[n] = ASRC[h * OUTC + n * 16 + r16];
        adc[n] = ADST[h * OUTC + n * 16 + r16];
    }

    // epilogue: D frag layout col=lane&15, row=(lane>>4)*4+j  [m89-verified]
#pragma unroll
    for (int m = 0; m < 4; ++m) {
#pragma unroll
        for (int j = 0; j < 4; ++j) {
            int row = m0 + m * 16 + g * 4 + j;
            float ds = 0.f, dd = 0.f;
#pragma unroll
            for (int n = 0; n < 4; ++n) {
                ds = fmaf(acc[m][n][j], asc[n], ds);
                dd = fmaf(acc[m][n][j], adc[n], dd);
            }
#pragma unroll
            for (int o = 1; o < 16; o <<= 1) {
                ds += __shfl_xor(ds, o);
                dd += __shfl_xor(dd, o);
            }
            if (row < N) {
                if (r16 == 0) {
                    a_s[(size_t)row * HEADS + h] = ds;
                    a_d[(size_t)row * HEADS + h] = dd;
                }
#pragma unroll
                for (int n = 0; n < 4; ++n) {
                    int col = wid * 64 + n * 16 + r16;
                    XLB[(size_t)row * HCC + col] = f2bf(acc[m][n][j]);
                }
            }
        }
    }
}

// ---------------------------------------------------------------------------
// CSR build v6.2 (R12-measured ~38us tail): scan + partition + per-bucket
// finalize. NBLK=64.
// ---------------------------------------------------------------------------

// scan of the NBUK*NBLK (bucket-major) counts -> base2d + per-bucket pbase
__global__ __launch_bounds__(1024) void k_pscan(const int* __restrict__ pcnt2d,
                                                int* __restrict__ base2d,
                                                int* __restrict__ pbase,
                                                int E) {
    __shared__ int s[1024];
    const int PT = (NBUK * NBLK) / 1024;  // 32 per thread
    int t = threadIdx.x;
    int c[PT];
    int sum = 0;
#pragma unroll
    for (int i = 0; i < PT; ++i) {
        c[i] = pcnt2d[t * PT + i];
        sum += c[i];
    }
    s[t] = sum;
    __syncthreads();
    for (int off = 1; off < 1024; off <<= 1) {
        int x = (t >= off) ? s[t - off] : 0;
        __syncthreads();
        s[t] += x;
        __syncthreads();
    }
    int run = s[t] - sum;  // exclusive
#pragma unroll
    for (int i = 0; i < PT; ++i) {
        int j = t * PT + i;
        base2d[j] = run;
        if ((j & (NBLK - 1)) == 0) pbase[j / NBLK] = run;
        run += c[i];
    }
    if (t == 0) pbase[NBUK] = E;
}

// sweep 2: write packed edges into exact block-private (bucket,block) segs
__global__ __launch_bounds__(256) void k_part2(const int* __restrict__ ei,
                                               const int* __restrict__ base2d,
                                               unsigned* __restrict__ pedges,
                                               int E, unsigned M, int rng) {
    __shared__ int cur[NBUK];
    int t = threadIdx.x;
    for (int k = t; k < NBUK; k += 256)
        cur[k] = base2d[k * NBLK + blockIdx.x];
    __syncthreads();
    int chunk = (E + NBLK - 1) / NBLK;
    int e0 = blockIdx.x * chunk;
    int e1 = e0 + chunk;
    if (e1 > E) e1 = E;
    for (int i = e0 + t; i < e1; i += 256) {
        int src = ei[i];
        int dst = ei[E + i];
        int s = buk_of(dst, M);
        int pos = atomicAdd(&cur[s], 1);  // LDS atomic only
        pedges[pos] = ((unsigned)(dst - s * rng) << SRC_BITS) | (unsigned)src;
    }
}

// per-bucket finalize: LDS histogram + scan -> rowptr, self-loops, eid.
// Bucket k's eid region = [pbase[k] + k*rng, ...) -- closed form, L2-local.
__global__ __launch_bounds__(256) void k_fin(const int* __restrict__ pbase,
                                             const unsigned* __restrict__ pedges,
                                             int* __restrict__ rowptr,
                                             int* __restrict__ eid,
                                             int N, int rng) {
    __shared__ int cntL[256];
    __shared__ int scanL[256];
    __shared__ int fillL[256];
    int k = blockIdx.x;
    int t = threadIdx.x;
    int lo = k * rng;
    if (lo >= N) return;
    int nloc = N - lo;
    if (nloc > rng) nloc = rng;
    int p0 = pbase[k];
    int cnt = pbase[k + 1] - p0;
    cntL[t] = 0;
    __syncthreads();
    for (int i = t; i < cnt; i += 256)
        atomicAdd(&cntL[pedges[p0 + i] >> SRC_BITS], 1);
    __syncthreads();
    int own = (t < nloc) ? cntL[t] + 1 : 0;  // +1 self-loop
    scanL[t] = own;
    __syncthreads();
    for (int off = 1; off < 256; off <<= 1) {
        int x = (t >= off) ? scanL[t - off] : 0;
        __syncthreads();
        scanL[t] += x;
        __syncthreads();
    }
    int excl = scanL[t] - own;
    int gbase = p0 + lo;  // edge prefix + self-loop prefix
    if (t < nloc) {
        rowptr[lo + t] = gbase + excl;
        if (lo + t == N - 1) rowptr[N] = gbase + excl + own;
        eid[gbase + excl] = lo + t;  // self-loop first
        fillL[t] = excl + 1;
    }
    __syncthreads();
    for (int i = t; i < cnt; i += 256) {
        unsigned pk = pedges[p0 + i];
        int dl = (int)(pk >> SRC_BITS);
        int pos = atomicAdd(&fillL[dl], 1);
        eid[gbase + pos] = (int)(pk & SRC_MASK);
    }
}

// ---------------------------------------------------------------------------
// Kernel 3: per-dst softmax + aggregation. One WAVE per node, lane owns 4
// channels. 8-deep edge unroll for gather MLP. No max subtraction (logits
// O(8), fp32 exp safe).
// ---------------------------------------------------------------------------
__global__ __launch_bounds__(256) void k_agg(const int* __restrict__ rowptr,
                                             const int* __restrict__ eid,
                                             const float* __restrict__ a_s,
                                             const float* __restrict__ a_d,
                                             const unsigned short* __restrict__ XLB,
                                             const float* __restrict__ BIAS,
                                             float* __restrict__ OUT, int N) {
    int wid = threadIdx.x >> 6;
    int lane = threadIdx.x & 63;
    int n = blockIdx.x * 4 + wid;
    if (n >= N) return;
    int h = lane >> 4;
    int s0 = rowptr[n];
    int s1 = rowptr[n + 1];
    float adn = a_d[(size_t)n * HEADS + h];
    float s = 0.f;
    float acc0 = 0.f, acc1 = 0.f, acc2 = 0.f, acc3 = 0.f;

    int e = s0;
    for (; e + 8 <= s1; e += 8) {
        int idx[8];
#pragma unroll
        for (int j = 0; j < 8; ++j) idx[j] = eid[e + j];
        float l[8];
#pragma unroll
        for (int j = 0; j < 8; ++j) l[j] = a_s[(size_t)idx[j] * HEADS + h] + adn;
        ushort4 xv[8];
#pragma unroll
        for (int j = 0; j < 8; ++j)
            xv[j] = *(const ushort4*)(XLB + (size_t)idx[j] * HCC + lane * 4);
#pragma unroll
        for (int j = 0; j < 8; ++j) {
            float lj = fmaxf(l[j], NEG_SLOPE * l[j]);
            float p = __expf(lj);
            s += p;
            acc0 = fmaf(p, bf2f(xv[j].x), acc0);
            acc1 = fmaf(p, bf2f(xv[j].y), acc1);
            acc2 = fmaf(p, bf2f(xv[j].z), acc2);
            acc3 = fmaf(p, bf2f(xv[j].w), acc3);
        }
    }
    for (; e + 4 <= s1; e += 4) {
        int idx[4];
#pragma unroll
        for (int j = 0; j < 4; ++j) idx[j] = eid[e + j];
        float l[4];
#pragma unroll
        for (int j = 0; j < 4; ++j) l[j] = a_s[(size_t)idx[j] * HEADS + h] + adn;
        ushort4 xv[4];
#pragma unroll
        for (int j = 0; j < 4; ++j)
            xv[j] = *(const ushort4*)(XLB + (size_t)idx[j] * HCC + lane * 4);
#pragma unroll
        for (int j = 0; j < 4; ++j) {
            float lj = fmaxf(l[j], NEG_SLOPE * l[j]);
            float p = __expf(lj);
            s += p;
            acc0 = fmaf(p, bf2f(xv[j].x), acc0);
            acc1 = fmaf(p, bf2f(xv[j].y), acc1);
            acc2 = fmaf(p, bf2f(xv[j].z), acc2);
            acc3 = fmaf(p, bf2f(xv[j].w), acc3);
        }
    }
    for (; e < s1; ++e) {
        int src = eid[e];
        float l = a_s[(size_t)src * HEADS + h] + adn;
        l = fmaxf(l, NEG_SLOPE * l);
        float p = __expf(l);
        ushort4 xv = *(const ushort4*)(XLB + (size_t)src * HCC + lane * 4);
        s += p;
        acc0 = fmaf(p, bf2f(xv.x), acc0);
        acc1 = fmaf(p, bf2f(xv.y), acc1);
        acc2 = fmaf(p, bf2f(xv.z), acc2);
        acc3 = fmaf(p, bf2f(xv.w), acc3);
    }

    float inv = 1.f / (s + 1e-16f);
    float4 b = *(const float4*)(BIAS + lane * 4);
    float4 o;
    o.x = acc0 * inv + b.x;
    o.y = acc1 * inv + b.y;
    o.z = acc2 * inv + b.z;
    o.w = acc3 * inv + b.w;
    *(float4*)(OUT + (size_t)n * HCC + lane * 4) = o;
}

// ---------------------------------------------------------------------------
extern "C" void kernel_launch(void* const* d_in, const int* in_sizes, int n_in,
                              void* d_out, int out_size, void* d_ws,
                              size_t ws_size, hipStream_t stream) {
    const float* X = (const float*)d_in[0];
    const int* EI = (const int*)d_in[1];
    const float* W = (const float*)d_in[2];
    const float* ASRC = (const float*)d_in[3];
    const float* ADST = (const float*)d_in[4];
    const float* BIAS = (const float*)d_in[5];
    float* OUT = (float*)d_out;

    const int N = in_sizes[0] / IN_CH;
    const int E = in_sizes[1] / 2;
    const int ET = E + N;
    const int rng = (N + NBUK - 1) / NBUK;
    const unsigned M = (unsigned)(((1ULL << 32) + rng - 1) / (unsigned)rng);

    // workspace layout (all 256B aligned)
    char* w = (char*)d_ws;
    auto align = [](size_t x) { return (x + 255) & ~(size_t)255; };
    size_t o = 0;
    unsigned short* xlb = (unsigned short*)(w + o); o += align((size_t)N * HCC * 2);
    unsigned short* wt = (unsigned short*)(w + o);  o += align((size_t)IN_CH * HCC * 2);
    float* a_s = (float*)(w + o); o += align((size_t)N * HEADS * 4);
    float* a_d = (float*)(w + o); o += align((size_t)N * HEADS * 4);
    int* rowptr = (int*)(w + o);  o += align((size_t)(N + 1) * 4);
    int* eid = (int*)(w + o);     o += align((size_t)ET * 4);
    unsigned* pedges = (unsigned*)(w + o); o += align((size_t)E * 4);
    int* pcnt2d = (int*)(w + o);  o += align((size_t)NBUK * NBLK * 4);
    int* base2d = (int*)(w + o);  o += align((size_t)NBUK * NBLK * 4);
    int* pbase = (int*)(w + o);   o += align((NBUK + 1) * 4);

    // 0. W -> WT (bf16, transposed)
    k_wt<<<HCC, IN_CH, 0, stream>>>(W, wt);

    // 1. fused: MFMA GEMM 64x256 (+att logits) || CSR bucket histogram
    int ngemm = (N + 63) / 64;
    k_gemm_pcnt<<<ngemm + NBLK, 256, 0, stream>>>(X, wt, ASRC, ADST, xlb,
                                                  a_s, a_d, N, ngemm, EI,
                                                  pcnt2d, E, M);

    // 2. CSR build v6.2
    k_pscan<<<1, 1024, 0, stream>>>(pcnt2d, base2d, pbase, E);
    k_part2<<<NBLK, 256, 0, stream>>>(EI, base2d, pedges, E, M, rng);
    k_fin<<<NBUK, 256, 0, stream>>>(pbase, pedges, rowptr, eid, N, rng);

    // 3. per-dst softmax + weighted aggregation (one wave per node)
    k_agg<<<(N + 3) / 4, 256, 0, stream>>>(rowptr, eid, a_s, a_d, xlb, BIAS,
                                           OUT, N);
}

// Round 14
// 311.719 us; speedup vs baseline: 1.1605x; 1.0089x over previous
//
#include <hip/hip_runtime.h>

#define IN_CH  256
#define HCC    256   // HEADS*OUT_CH
#define HEADS  4
#define OUTC   64
#define NEG_SLOPE 0.2f

#define NBUK   512    // dst buckets (rng = ceil(N/512) nodes each)
#define NBLK   64     // partition blocks (segment ~195B -> mostly-full lines)
#define SRC_BITS 17
#define SRC_MASK 0x1FFFF

using short8v = __attribute__((ext_vector_type(8))) short;
using f32x4   = __attribute__((ext_vector_type(4))) float;

__device__ __forceinline__ unsigned short f2bf(float f) {
    unsigned u = __float_as_uint(f);
    unsigned r = (u + 0x7fffu + ((u >> 16) & 1u)) >> 16;  // RNE
    return (unsigned short)r;
}
__device__ __forceinline__ float bf2f(unsigned short b) {
    return __uint_as_float((unsigned)b << 16);
}
__device__ __forceinline__ int buk_of(int dst, unsigned M) {
    unsigned s = (unsigned)(((unsigned long long)(unsigned)dst * M) >> 32);
    return (s >= NBUK) ? (NBUK - 1) : (int)s;
}
__device__ __forceinline__ void gload_lds16(const unsigned short* g,
                                            unsigned short* lds) {
    __builtin_amdgcn_global_load_lds(
        (const __attribute__((address_space(1))) unsigned*)g,
        (__attribute__((address_space(3))) unsigned*)lds, 16, 0, 0);
}

// ---------------------------------------------------------------------------
// Kernel 0: W [K=256][N=256] fp32 -> WT [N][K] bf16 (tiny, one-time)
// ---------------------------------------------------------------------------
__global__ void k_wt(const float* __restrict__ W,
                     unsigned short* __restrict__ WT) {
    int n = blockIdx.x;
    int k = threadIdx.x;
    WT[n * IN_CH + k] = f2bf(W[(size_t)k * HCC + n]);
}

// ---------------------------------------------------------------------------
// Kernel 1 (fused, BM=64): heterogeneous grid.
//   blocks [0, ngemm):          MFMA GEMM tile 64x256 + fused att logits
//   blocks [ngemm, ngemm+NBLK): dst-bucket histogram (CSR sweep 1)
// B staged via global_load_lds (width 16) into LINEAR LDS with XOR-swizzled
// SOURCE (rule-21 pattern): dest[row][c] = src[row][c^(row&7)]; reads fetch
// chunk k^(r16&7) -> 2-way banks (free). Kills 8 ds_write_b128 + 8 VGPR
// round-trips per thread per K-step.
// ---------------------------------------------------------------------------
__global__ __launch_bounds__(256) void k_gemm_pcnt(
    const float* __restrict__ X, const unsigned short* __restrict__ WT,
    const float* __restrict__ ASRC, const float* __restrict__ ADST,
    unsigned short* __restrict__ XLB, float* __restrict__ a_s,
    float* __restrict__ a_d, int N, int ngemm,
    const int* __restrict__ ei, int* __restrict__ pcnt2d, int E, unsigned M) {
    __shared__ unsigned short Ats[64][72];          // [m][k], padded
    __shared__ __align__(16) unsigned short Bs[256 * 64];  // linear [n][k]
    __shared__ int hbuk[NBUK];

    if (blockIdx.x >= ngemm) {
        // ---- CSR sweep 1: per-(bucket,block) counts via LDS histogram ----
        int bid = blockIdx.x - ngemm;
        int t = threadIdx.x;
        for (int k = t; k < NBUK; k += 256) hbuk[k] = 0;
        __syncthreads();
        int chunk = (E + NBLK - 1) / NBLK;
        int e0 = bid * chunk;
        int e1 = e0 + chunk;
        if (e1 > E) e1 = E;
        for (int i = e0 + t; i < e1; i += 256)
            atomicAdd(&hbuk[buk_of(ei[E + i], M)], 1);
        __syncthreads();
        for (int k = t; k < NBUK; k += 256)
            pcnt2d[k * NBLK + bid] = hbuk[k];
        return;
    }

    // ---- GEMM tile: 64 rows x 256 cols ----
    const int tid = threadIdx.x;
    const int lane = tid & 63;
    const int wid = tid >> 6;
    const int m0 = blockIdx.x * 64;
    const int r16 = lane & 15;
    const int g = lane >> 4;
    const int l8 = lane >> 3;       // 0..7: dest row within 8-row group
    const int cs = (lane & 7) ^ l8; // swizzled source chunk

    f32x4 acc[4][4];
    const f32x4 z = {0.f, 0.f, 0.f, 0.f};
#pragma unroll
    for (int m = 0; m < 4; ++m)
#pragma unroll
        for (int n = 0; n < 4; ++n) acc[m][n] = z;

    for (int kb = 0; kb < IN_CH; kb += 64) {
        // B: 8 issues/wave of 1024B direct global->LDS, swizzled source
#pragma unroll
        for (int i = 0; i < 8; ++i) {
            int r0 = wid * 64 + i * 8;              // wave-uniform
            int row = r0 + l8;
            gload_lds16(WT + (size_t)row * IN_CH + kb + cs * 8,
                        &Bs[r0 * 64]);
        }
        // A: 64 rows x 64 k, fp32 -> bf16 (reg-staged, needs convert)
#pragma unroll
        for (int it = 0; it < 4; ++it) {
            int v = tid + 256 * it;
            int row = v >> 4;
            int c4 = (v & 15) << 2;
            int gr = m0 + row;
            float4 av = make_float4(0.f, 0.f, 0.f, 0.f);
            if (gr < N) av = *(const float4*)(X + (size_t)gr * IN_CH + kb + c4);
            ushort4 ab;
            ab.x = f2bf(av.x); ab.y = f2bf(av.y);
            ab.z = f2bf(av.z); ab.w = f2bf(av.w);
            *(ushort4*)&Ats[row][c4] = ab;
        }
        __syncthreads();   // drains vmcnt (incl. global_load_lds) + lgkm
#pragma unroll
        for (int ks = 0; ks < 2; ++ks) {
            short8v af[4], bf[4];
#pragma unroll
            for (int m = 0; m < 4; ++m)
                af[m] = *(const short8v*)&Ats[m * 16 + r16][ks * 32 + g * 8];
#pragma unroll
            for (int n = 0; n < 4; ++n) {
                int row = wid * 64 + n * 16 + r16;
                int ck = (ks * 4 + g) ^ (r16 & 7);  // de-swizzle on read
                bf[n] = *(const short8v*)&Bs[row * 64 + ck * 8];
            }
#pragma unroll
            for (int m = 0; m < 4; ++m)
#pragma unroll
                for (int n = 0; n < 4; ++n)
                    acc[m][n] = __builtin_amdgcn_mfma_f32_16x16x32_bf16(
                        af[m], bf[n], acc[m][n], 0, 0, 0);
        }
        __syncthreads();
    }

    const int h = wid;
    float asc[4], adc[4];
#pragma unroll
    for (int n = 0; n < 4; ++n) {
        asc[n] = ASRC[h * OUTC + n * 16 + r16];
        adc[n] = ADST[h * OUTC + n * 16 + r16];
    }

    // epilogue: D frag layout col=lane&15, row=(lane>>4)*4+j  [m89-verified]
#pragma unroll
    for (int m = 0; m < 4; ++m) {
#pragma unroll
        for (int j = 0; j < 4; ++j) {
            int row = m0 + m * 16 + g * 4 + j;
            float ds = 0.f, dd = 0.f;
#pragma unroll
            for (int n = 0; n < 4; ++n) {
                ds = fmaf(acc[m][n][j], asc[n], ds);
                dd = fmaf(acc[m][n][j], adc[n], dd);
            }
#pragma unroll
            for (int o = 1; o < 16; o <<= 1) {
                ds += __shfl_xor(ds, o);
                dd += __shfl_xor(dd, o);
            }
            if (row < N) {
                if (r16 == 0) {
                    a_s[(size_t)row * HEADS + h] = ds;
                    a_d[(size_t)row * HEADS + h] = dd;
                }
#pragma unroll
                for (int n = 0; n < 4; ++n) {
                    int col = wid * 64 + n * 16 + r16;
                    XLB[(size_t)row * HCC + col] = f2bf(acc[m][n][j]);
                }
            }
        }
    }
}

// ---------------------------------------------------------------------------
// CSR build v6.2 (R12-measured ~37us tail): scan + partition + per-bucket
// finalize. NBLK=64.
// ---------------------------------------------------------------------------

// scan of the NBUK*NBLK (bucket-major) counts -> base2d + per-bucket pbase
__global__ __launch_bounds__(1024) void k_pscan(const int* __restrict__ pcnt2d,
                                                int* __restrict__ base2d,
                                                int* __restrict__ pbase,
                                                int E) {
    __shared__ int s[1024];
    const int PT = (NBUK * NBLK) / 1024;  // 32 per thread
    int t = threadIdx.x;
    int c[PT];
    int sum = 0;
#pragma unroll
    for (int i = 0; i < PT; ++i) {
        c[i] = pcnt2d[t * PT + i];
        sum += c[i];
    }
    s[t] = sum;
    __syncthreads();
    for (int off = 1; off < 1024; off <<= 1) {
        int x = (t >= off) ? s[t - off] : 0;
        __syncthreads();
        s[t] += x;
        __syncthreads();
    }
    int run = s[t] - sum;  // exclusive
#pragma unroll
    for (int i = 0; i < PT; ++i) {
        int j = t * PT + i;
        base2d[j] = run;
        if ((j & (NBLK - 1)) == 0) pbase[j / NBLK] = run;
        run += c[i];
    }
    if (t == 0) pbase[NBUK] = E;
}

// sweep 2: write packed edges into exact block-private (bucket,block) segs
__global__ __launch_bounds__(256) void k_part2(const int* __restrict__ ei,
                                               const int* __restrict__ base2d,
                                               unsigned* __restrict__ pedges,
                                               int E, unsigned M, int rng) {
    __shared__ int cur[NBUK];
    int t = threadIdx.x;
    for (int k = t; k < NBUK; k += 256)
        cur[k] = base2d[k * NBLK + blockIdx.x];
    __syncthreads();
    int chunk = (E + NBLK - 1) / NBLK;
    int e0 = blockIdx.x * chunk;
    int e1 = e0 + chunk;
    if (e1 > E) e1 = E;
    for (int i = e0 + t; i < e1; i += 256) {
        int src = ei[i];
        int dst = ei[E + i];
        int s = buk_of(dst, M);
        int pos = atomicAdd(&cur[s], 1);  // LDS atomic only
        pedges[pos] = ((unsigned)(dst - s * rng) << SRC_BITS) | (unsigned)src;
    }
}

// per-bucket finalize: LDS histogram + scan -> rowptr, self-loops, eid.
// Bucket k's eid region = [pbase[k] + k*rng, ...) -- closed form, L2-local.
__global__ __launch_bounds__(256) void k_fin(const int* __restrict__ pbase,
                                             const unsigned* __restrict__ pedges,
                                             int* __restrict__ rowptr,
                                             int* __restrict__ eid,
                                             int N, int rng) {
    __shared__ int cntL[256];
    __shared__ int scanL[256];
    __shared__ int fillL[256];
    int k = blockIdx.x;
    int t = threadIdx.x;
    int lo = k * rng;
    if (lo >= N) return;
    int nloc = N - lo;
    if (nloc > rng) nloc = rng;
    int p0 = pbase[k];
    int cnt = pbase[k + 1] - p0;
    cntL[t] = 0;
    __syncthreads();
    for (int i = t; i < cnt; i += 256)
        atomicAdd(&cntL[pedges[p0 + i] >> SRC_BITS], 1);
    __syncthreads();
    int own = (t < nloc) ? cntL[t] + 1 : 0;  // +1 self-loop
    scanL[t] = own;
    __syncthreads();
    for (int off = 1; off < 256; off <<= 1) {
        int x = (t >= off) ? scanL[t - off] : 0;
        __syncthreads();
        scanL[t] += x;
        __syncthreads();
    }
    int excl = scanL[t] - own;
    int gbase = p0 + lo;  // edge prefix + self-loop prefix
    if (t < nloc) {
        rowptr[lo + t] = gbase + excl;
        if (lo + t == N - 1) rowptr[N] = gbase + excl + own;
        eid[gbase + excl] = lo + t;  // self-loop first
        fillL[t] = excl + 1;
    }
    __syncthreads();
    for (int i = t; i < cnt; i += 256) {
        unsigned pk = pedges[p0 + i];
        int dl = (int)(pk >> SRC_BITS);
        int pos = atomicAdd(&fillL[dl], 1);
        eid[gbase + pos] = (int)(pk & SRC_MASK);
    }
}

// ---------------------------------------------------------------------------
// Kernel 3: per-dst softmax + aggregation. One WAVE per node, lane owns 4
// channels. 8-deep edge unroll for gather MLP. No max subtraction (logits
// O(8), fp32 exp safe).
// ---------------------------------------------------------------------------
__global__ __launch_bounds__(256) void k_agg(const int* __restrict__ rowptr,
                                             const int* __restrict__ eid,
                                             const float* __restrict__ a_s,
                                             const float* __restrict__ a_d,
                                             const unsigned short* __restrict__ XLB,
                                             const float* __restrict__ BIAS,
                                             float* __restrict__ OUT, int N) {
    int wid = threadIdx.x >> 6;
    int lane = threadIdx.x & 63;
    int n = blockIdx.x * 4 + wid;
    if (n >= N) return;
    int h = lane >> 4;
    int s0 = rowptr[n];
    int s1 = rowptr[n + 1];
    float adn = a_d[(size_t)n * HEADS + h];
    float s = 0.f;
    float acc0 = 0.f, acc1 = 0.f, acc2 = 0.f, acc3 = 0.f;

    int e = s0;
    for (; e + 8 <= s1; e += 8) {
        int idx[8];
#pragma unroll
        for (int j = 0; j < 8; ++j) idx[j] = eid[e + j];
        float l[8];
#pragma unroll
        for (int j = 0; j < 8; ++j) l[j] = a_s[(size_t)idx[j] * HEADS + h] + adn;
        ushort4 xv[8];
#pragma unroll
        for (int j = 0; j < 8; ++j)
            xv[j] = *(const ushort4*)(XLB + (size_t)idx[j] * HCC + lane * 4);
#pragma unroll
        for (int j = 0; j < 8; ++j) {
            float lj = fmaxf(l[j], NEG_SLOPE * l[j]);
            float p = __expf(lj);
            s += p;
            acc0 = fmaf(p, bf2f(xv[j].x), acc0);
            acc1 = fmaf(p, bf2f(xv[j].y), acc1);
            acc2 = fmaf(p, bf2f(xv[j].z), acc2);
            acc3 = fmaf(p, bf2f(xv[j].w), acc3);
        }
    }
    for (; e + 4 <= s1; e += 4) {
        int idx[4];
#pragma unroll
        for (int j = 0; j < 4; ++j) idx[j] = eid[e + j];
        float l[4];
#pragma unroll
        for (int j = 0; j < 4; ++j) l[j] = a_s[(size_t)idx[j] * HEADS + h] + adn;
        ushort4 xv[4];
#pragma unroll
        for (int j = 0; j < 4; ++j)
            xv[j] = *(const ushort4*)(XLB + (size_t)idx[j] * HCC + lane * 4);
#pragma unroll
        for (int j = 0; j < 4; ++j) {
            float lj = fmaxf(l[j], NEG_SLOPE * l[j]);
            float p = __expf(lj);
            s += p;
            acc0 = fmaf(p, bf2f(xv[j].x), acc0);
            acc1 = fmaf(p, bf2f(xv[j].y), acc1);
            acc2 = fmaf(p, bf2f(xv[j].z), acc2);
            acc3 = fmaf(p, bf2f(xv[j].w), acc3);
        }
    }
    for (; e < s1; ++e) {
        int src = eid[e];
        float l = a_s[(size_t)src * HEADS + h] + adn;
        l = fmaxf(l, NEG_SLOPE * l);
        float p = __expf(l);
        ushort4 xv = *(const ushort4*)(XLB + (size_t)src * HCC + lane * 4);
        s += p;
        acc0 = fmaf(p, bf2f(xv.x), acc0);
        acc1 = fmaf(p, bf2f(xv.y), acc1);
        acc2 = fmaf(p, bf2f(xv.z), acc2);
        acc3 = fmaf(p, bf2f(xv.w), acc3);
    }

    float inv = 1.f / (s + 1e-16f);
    float4 b = *(const float4*)(BIAS + lane * 4);
    float4 o;
    o.x = acc0 * inv + b.x;
    o.y = acc1 * inv + b.y;
    o.z = acc2 * inv + b.z;
    o.w = acc3 * inv + b.w;
    *(float4*)(OUT + (size_t)n * HCC + lane * 4) = o;
}

// ---------------------------------------------------------------------------
extern "C" void kernel_launch(void* const* d_in, const int* in_sizes, int n_in,
                              void* d_out, int out_size, void* d_ws,
                              size_t ws_size, hipStream_t stream) {
    const float* X = (const float*)d_in[0];
    const int* EI = (const int*)d_in[1];
    const float* W = (const float*)d_in[2];
    const float* ASRC = (const float*)d_in[3];
    const float* ADST = (const float*)d_in[4];
    const float* BIAS = (const float*)d_in[5];
    float* OUT = (float*)d_out;

    const int N = in_sizes[0] / IN_CH;
    const int E = in_sizes[1] / 2;
    const int ET = E + N;
    const int rng = (N + NBUK - 1) / NBUK;
    const unsigned M = (unsigned)(((1ULL << 32) + rng - 1) / (unsigned)rng);

    // workspace layout (all 256B aligned)
    char* w = (char*)d_ws;
    auto align = [](size_t x) { return (x + 255) & ~(size_t)255; };
    size_t o = 0;
    unsigned short* xlb = (unsigned short*)(w + o); o += align((size_t)N * HCC * 2);
    unsigned short* wt = (unsigned short*)(w + o);  o += align((size_t)IN_CH * HCC * 2);
    float* a_s = (float*)(w + o); o += align((size_t)N * HEADS * 4);
    float* a_d = (float*)(w + o); o += align((size_t)N * HEADS * 4);
    int* rowptr = (int*)(w + o);  o += align((size_t)(N + 1) * 4);
    int* eid = (int*)(w + o);     o += align((size_t)ET * 4);
    unsigned* pedges = (unsigned*)(w + o); o += align((size_t)E * 4);
    int* pcnt2d = (int*)(w + o);  o += align((size_t)NBUK * NBLK * 4);
    int* base2d = (int*)(w + o);  o += align((size_t)NBUK * NBLK * 4);
    int* pbase = (int*)(w + o);   o += align((NBUK + 1) * 4);

    // 0. W -> WT (bf16, transposed)
    k_wt<<<HCC, IN_CH, 0, stream>>>(W, wt);

    // 1. fused: MFMA GEMM 64x256 (+att logits, gload_lds B) || CSR histogram
    int ngemm = (N + 63) / 64;
    k_gemm_pcnt<<<ngemm + NBLK, 256, 0, stream>>>(X, wt, ASRC, ADST, xlb,
                                                  a_s, a_d, N, ngemm, EI,
                                                  pcnt2d, E, M);

    // 2. CSR build v6.2
    k_pscan<<<1, 1024, 0, stream>>>(pcnt2d, base2d, pbase, E);
    k_part2<<<NBLK, 256, 0, stream>>>(EI, base2d, pedges, E, M, rng);
    k_fin<<<NBUK, 256, 0, stream>>>(pbase, pedges, rowptr, eid, N, rng);

    // 3. per-dst softmax + weighted aggregation (one wave per node)
    k_agg<<<(N + 3) / 4, 256, 0, stream>>>(rowptr, eid, a_s, a_d, xlb, BIAS,
                                           OUT, N);
}